// Round 7
// baseline (159.724 us; speedup 1.0000x reference)
//
#include <hip/hip_runtime.h>
#include <hip/hip_cooperative_groups.h>

namespace cg = cooperative_groups;

// QTLayer, cooperative single-launch tensor-train composition:
//   out[b] = core0[s0]·M1(s1)·M2(s2)·c3(a) = w[s0*256+s1] · u[s2*64+a]
// w = core0·core1 (64K rows), u = core2·core3 (16K rows), bf16x8 rows (16 B)
// -> one dwordx4 gather per table per sample (2 scattered lines/sample).
//
// ONE cooperative kernel, 1024 blocks x 256 threads:
//   phase A: blocks [0,256) build w (1 row/thread), [256,320) build u
//            (1 row/thread); ALL blocks issue their streaming index loads
//            first so the 16 MB index stream hides under the build.
//   grid.sync()  -- proper generation-based barrier, correct cross-XCD
//            memory ordering, race-free on graph replays (unlike the R6
//            hand-rolled token spin, which raced rebuilds vs gathers).
//   phase B: 4 samples/thread: 8 independent table gathers + dot8 + store.
// Capacity: 1024 blocks, 4 waves each at ~70 VGPR -> ~7 blocks/CU capacity
// (1792) >= 1024, so cooperative launch is valid.
// If cooperative launch fails (capture quirk), fall back to the two-kernel
// split path in the same call.

#define QT_B (1 << 20)
#define NS 256
#define NA 64

#define W_ROWS (NS * NS)   // 65536
#define U_ROWS (NS * NA)   // 16384
#define MAIN_BLOCKS (QT_B / 4 / 256)   // 1024

typedef int   vint4   __attribute__((ext_vector_type(4)));
typedef float vfloat4 __attribute__((ext_vector_type(4)));

__device__ __forceinline__ unsigned short f2bf(float x) {
    unsigned int u = __float_as_uint(x);
    unsigned int r = (u + 0x7fffu + ((u >> 16) & 1u)) >> 16;  // RNE
    return (unsigned short)r;
}

__device__ __forceinline__ float bf_lo(unsigned int u) {
    return __uint_as_float(u << 16);
}
__device__ __forceinline__ float bf_hi(unsigned int u) {
    return __uint_as_float(u & 0xffff0000u);
}

__device__ __forceinline__ float dot8bf(uint4 wv, uint4 uv) {
    float acc;
    acc = bf_lo(wv.x) * bf_lo(uv.x);
    acc = fmaf(bf_hi(wv.x), bf_hi(uv.x), acc);
    acc = fmaf(bf_lo(wv.y), bf_lo(uv.y), acc);
    acc = fmaf(bf_hi(wv.y), bf_hi(uv.y), acc);
    acc = fmaf(bf_lo(wv.z), bf_lo(uv.z), acc);
    acc = fmaf(bf_hi(wv.z), bf_hi(uv.z), acc);
    acc = fmaf(bf_lo(wv.w), bf_lo(uv.w), acc);
    acc = fmaf(bf_hi(wv.w), bf_hi(uv.w), acc);
    return acc;
}

__device__ __forceinline__ uint4 pack8bf(const float acc[8]) {
    uint4 p;
    p.x = (unsigned)f2bf(acc[0]) | ((unsigned)f2bf(acc[1]) << 16);
    p.y = (unsigned)f2bf(acc[2]) | ((unsigned)f2bf(acc[3]) << 16);
    p.z = (unsigned)f2bf(acc[4]) | ((unsigned)f2bf(acc[5]) << 16);
    p.w = (unsigned)f2bf(acc[6]) | ((unsigned)f2bf(acc[7]) << 16);
    return p;
}

// ---------------- shared build helpers (identical math to the split path)
__device__ __forceinline__ void build_w_row(
    const float* __restrict__ core0, const float* __restrict__ core1,
    int s0, int s1, uint4* __restrict__ wbf)
{
    float acc[8] = {0.f, 0.f, 0.f, 0.f, 0.f, 0.f, 0.f, 0.f};
#pragma unroll
    for (int r = 0; r < 8; ++r) {
        const float c = core0[s0 * 8 + r];
        const float* row = core1 + (r * (NS * 8) + s1 * 8);
        const float4 lo = *(const float4*)row;
        const float4 hi = *(const float4*)(row + 4);
        acc[0] = fmaf(c, lo.x, acc[0]);
        acc[1] = fmaf(c, lo.y, acc[1]);
        acc[2] = fmaf(c, lo.z, acc[2]);
        acc[3] = fmaf(c, lo.w, acc[3]);
        acc[4] = fmaf(c, hi.x, acc[4]);
        acc[5] = fmaf(c, hi.y, acc[5]);
        acc[6] = fmaf(c, hi.z, acc[6]);
        acc[7] = fmaf(c, hi.w, acc[7]);
    }
    wbf[s0 * NS + s1] = pack8bf(acc);
}

__device__ __forceinline__ void build_u_row(
    const float* __restrict__ core2, const float* __restrict__ core3,
    int q, uint4* __restrict__ ubf)
{
    const int s2 = q >> 6;
    const int a  = q & (NA - 1);
    float c3[8];
#pragma unroll
    for (int s = 0; s < 8; ++s) c3[s] = core3[s * NA + a];
    float acc[8];
#pragma unroll
    for (int r = 0; r < 8; ++r) {
        const float* row = core2 + (r * (NS * 8) + s2 * 8);
        const float4 lo = *(const float4*)row;
        const float4 hi = *(const float4*)(row + 4);
        acc[r] = lo.x * c3[0] + lo.y * c3[1] + lo.z * c3[2] + lo.w * c3[3] +
                 hi.x * c3[4] + hi.y * c3[5] + hi.z * c3[6] + hi.w * c3[7];
    }
    ubf[q] = pack8bf(acc);
}

// ---------------- cooperative fused kernel ----------------
__global__ __launch_bounds__(256, 4) void qt_coop(
    const vint4* __restrict__ states4,
    const vint4* __restrict__ actions4,
    const float* __restrict__ core0,
    const float* __restrict__ core1,
    const float* __restrict__ core2,
    const float* __restrict__ core3,
    uint4* __restrict__ wbf,
    uint4* __restrict__ ubf,
    vfloat4* __restrict__ out4)
{
    const int blk = blockIdx.x;
    const int tid = threadIdx.x;
    const int t   = blk * 256 + tid;   // t < B/4 == grid threads

    // Issue streaming index loads FIRST — they complete under phase A + sync.
    const vint4 sa = __builtin_nontemporal_load(&states4[3 * t + 0]);
    const vint4 sb = __builtin_nontemporal_load(&states4[3 * t + 1]);
    const vint4 sc = __builtin_nontemporal_load(&states4[3 * t + 2]);
    const vint4 ac = __builtin_nontemporal_load(&actions4[t]);

    // Phase A: table build (blocks 0..319), 1 row per thread.
    if (blk < NS) {
        build_w_row(core0, core1, /*s0=*/blk, /*s1=*/tid, wbf);
    } else if (blk < NS + U_ROWS / 256) {
        build_u_row(core2, core3, (blk - NS) * 256 + tid, ubf);
    }

    cg::this_grid().sync();

    // Phase B: 4 samples/thread.
    // sample 0: (sa.x, sa.y, sa.z, ac.x)
    // sample 1: (sa.w, sb.x, sb.y, ac.y)
    // sample 2: (sb.z, sb.w, sc.x, ac.z)
    // sample 3: (sc.y, sc.z, sc.w, ac.w)
    const uint4 w0 = wbf[sa.x * NS + sa.y];
    const uint4 u0 = ubf[sa.z * NA + ac.x];
    const uint4 w1 = wbf[sa.w * NS + sb.x];
    const uint4 u1 = ubf[sb.y * NA + ac.y];
    const uint4 w2 = wbf[sb.z * NS + sb.w];
    const uint4 u2 = ubf[sc.x * NA + ac.z];
    const uint4 w3 = wbf[sc.y * NS + sc.z];
    const uint4 u3 = ubf[sc.w * NA + ac.w];

    vfloat4 o;
    o.x = dot8bf(w0, u0);
    o.y = dot8bf(w1, u1);
    o.z = dot8bf(w2, u2);
    o.w = dot8bf(w3, u3);

    __builtin_nontemporal_store(o, &out4[t]);
}

// ---------------- split-path fallback kernels (R5 structure) ----------------
__global__ __launch_bounds__(256) void qt_make_tables(
    const float* __restrict__ core0,
    const float* __restrict__ core1,
    const float* __restrict__ core2,
    const float* __restrict__ core3,
    uint4* __restrict__ wbf,
    uint4* __restrict__ ubf)
{
    const int blk = blockIdx.x;
    if (blk < NS) {
        build_w_row(core0, core1, blk, threadIdx.x, wbf);
    } else {
        build_u_row(core2, core3, (blk - NS) * 256 + threadIdx.x, ubf);
    }
}

__global__ __launch_bounds__(256) void qt_main4(
    const vint4* __restrict__ states4,
    const vint4* __restrict__ actions4,
    const uint4* __restrict__ wbf,
    const uint4* __restrict__ ubf,
    vfloat4* __restrict__ out4)
{
    const int t = blockIdx.x * blockDim.x + threadIdx.x;

    const vint4 sa = __builtin_nontemporal_load(&states4[3 * t + 0]);
    const vint4 sb = __builtin_nontemporal_load(&states4[3 * t + 1]);
    const vint4 sc = __builtin_nontemporal_load(&states4[3 * t + 2]);
    const vint4 ac = __builtin_nontemporal_load(&actions4[t]);

    const uint4 w0 = wbf[sa.x * NS + sa.y];
    const uint4 u0 = ubf[sa.z * NA + ac.x];
    const uint4 w1 = wbf[sa.w * NS + sb.x];
    const uint4 u1 = ubf[sb.y * NA + ac.y];
    const uint4 w2 = wbf[sb.z * NS + sb.w];
    const uint4 u2 = ubf[sc.x * NA + ac.z];
    const uint4 w3 = wbf[sc.y * NS + sc.z];
    const uint4 u3 = ubf[sc.w * NA + ac.w];

    vfloat4 o;
    o.x = dot8bf(w0, u0);
    o.y = dot8bf(w1, u1);
    o.z = dot8bf(w2, u2);
    o.w = dot8bf(w3, u3);

    __builtin_nontemporal_store(o, &out4[t]);
}

// ---------- fallback (round-1 kernel) if ws is too small
__global__ __launch_bounds__(256) void qt_direct(
    const int* __restrict__ states,
    const int* __restrict__ actions,
    const float* __restrict__ core0,
    const float* __restrict__ core1,
    const float* __restrict__ core2,
    const float* __restrict__ core3,
    float* __restrict__ out)
{
    const int b = blockIdx.x * blockDim.x + threadIdx.x;
    if (b >= QT_B) return;

    const int s0 = states[3 * b + 0];
    const int s1 = states[3 * b + 1];
    const int s2 = states[3 * b + 2];
    const int a  = actions[b];

    const float4 v0lo = *(const float4*)(core0 + s0 * 8);
    const float4 v0hi = *(const float4*)(core0 + s0 * 8 + 4);
    float v0[8] = {v0lo.x, v0lo.y, v0lo.z, v0lo.w,
                   v0hi.x, v0hi.y, v0hi.z, v0hi.w};

    float v1[8] = {0.f};
#pragma unroll
    for (int r = 0; r < 8; ++r) {
        const float* row = core1 + (r * (NS * 8) + s1 * 8);
        const float4 lo = *(const float4*)row;
        const float4 hi = *(const float4*)(row + 4);
        const float c = v0[r];
        v1[0] = fmaf(c, lo.x, v1[0]); v1[1] = fmaf(c, lo.y, v1[1]);
        v1[2] = fmaf(c, lo.z, v1[2]); v1[3] = fmaf(c, lo.w, v1[3]);
        v1[4] = fmaf(c, hi.x, v1[4]); v1[5] = fmaf(c, hi.y, v1[5]);
        v1[6] = fmaf(c, hi.z, v1[6]); v1[7] = fmaf(c, hi.w, v1[7]);
    }

    float v2[8] = {0.f};
#pragma unroll
    for (int r = 0; r < 8; ++r) {
        const float* row = core2 + (r * (NS * 8) + s2 * 8);
        const float4 lo = *(const float4*)row;
        const float4 hi = *(const float4*)(row + 4);
        const float c = v1[r];
        v2[0] = fmaf(c, lo.x, v2[0]); v2[1] = fmaf(c, lo.y, v2[1]);
        v2[2] = fmaf(c, lo.z, v2[2]); v2[3] = fmaf(c, lo.w, v2[3]);
        v2[4] = fmaf(c, hi.x, v2[4]); v2[5] = fmaf(c, hi.y, v2[5]);
        v2[6] = fmaf(c, hi.z, v2[6]); v2[7] = fmaf(c, hi.w, v2[7]);
    }

    float acc = 0.f;
#pragma unroll
    for (int r = 0; r < 8; ++r) acc = fmaf(v2[r], core3[r * NA + a], acc);
    out[b] = acc;
}

extern "C" void kernel_launch(void* const* d_in, const int* in_sizes, int n_in,
                              void* d_out, int out_size, void* d_ws, size_t ws_size,
                              hipStream_t stream) {
    const int*   states  = (const int*)d_in[0];
    const int*   actions = (const int*)d_in[1];
    const float* core0   = (const float*)d_in[2];
    const float* core1   = (const float*)d_in[3];
    const float* core2   = (const float*)d_in[4];
    const float* core3   = (const float*)d_in[5];
    float* out = (float*)d_out;

    const size_t need = (size_t)(W_ROWS + U_ROWS) * 16;  // 1.25 MB
    if (ws_size < need) {
        qt_direct<<<QT_B / 256, 256, 0, stream>>>(states, actions, core0, core1,
                                                  core2, core3, out);
        return;
    }

    uint4* wbf = (uint4*)d_ws;
    uint4* ubf = wbf + W_ROWS;

    const vint4* states4  = (const vint4*)states;
    const vint4* actions4 = (const vint4*)actions;
    vfloat4*     out4     = (vfloat4*)out;

    void* args[] = {(void*)&states4, (void*)&actions4,
                    (void*)&core0, (void*)&core1, (void*)&core2, (void*)&core3,
                    (void*)&wbf, (void*)&ubf, (void*)&out4};

    hipError_t err = hipLaunchCooperativeKernel(
        (const void*)qt_coop, dim3(MAIN_BLOCKS), dim3(256), args, 0, stream);

    if (err != hipSuccess) {
        // Fallback: R5 split path (two kernel nodes).
        qt_make_tables<<<NS + U_ROWS / 256, 256, 0, stream>>>(
            core0, core1, core2, core3, wbf, ubf);
        qt_main4<<<MAIN_BLOCKS, 256, 0, stream>>>(
            states4, actions4, wbf, ubf, out4);
    }
}

// Round 8
// 26.105 us; speedup vs baseline: 6.1185x; 6.1185x over previous
//
#include <hip/hip_runtime.h>

// QTLayer via tensor-train composition, bf16 tables, 4 samples/thread:
//   out[b] = core0[s0]·M1(s1)·M2(s2)·c3(a) = w[s0*256+s1] · u[s2*64+a]
// w = core0·core1 (64K rows), u = core2·core3 (16K rows), bf16x8 rows (16 B).
// Two-kernel split (fusion refuted twice: R6 token-spin raced rebuilds,
// R7 grid.sync cost ~120us). R8 change: table gathers use NONTEMPORAL
// loads to bypass L1 — tables (1.25 MB) never fit the 32 KiB L1, and each
// L1 miss fills a 128 B line of which we use 16 B -> 256 MB of L2->L1 fill
// traffic (~7.4 us at L2 ceiling) was the gather-phase floor. nt loads
// stream 64 B sectors from L2 instead. Tables remain L2-resident.
// NOTE: __builtin_nontemporal_* requires clang ext_vector types, not
// HIP_vector_type structs.

#define QT_B (1 << 20)
#define NS 256
#define NA 64

#define W_ROWS (NS * NS)   // 65536
#define U_ROWS (NS * NA)   // 16384
#define MAIN_BLOCKS (QT_B / 4 / 256)   // 1024

typedef int          vint4   __attribute__((ext_vector_type(4)));
typedef unsigned int vuint4  __attribute__((ext_vector_type(4)));
typedef float        vfloat4 __attribute__((ext_vector_type(4)));

__device__ __forceinline__ unsigned short f2bf(float x) {
    unsigned int u = __float_as_uint(x);
    unsigned int r = (u + 0x7fffu + ((u >> 16) & 1u)) >> 16;  // RNE
    return (unsigned short)r;
}

__device__ __forceinline__ float bf_lo(unsigned int u) {
    return __uint_as_float(u << 16);
}
__device__ __forceinline__ float bf_hi(unsigned int u) {
    return __uint_as_float(u & 0xffff0000u);
}

__device__ __forceinline__ float dot8bf(vuint4 wv, vuint4 uv) {
    float acc;
    acc = bf_lo(wv.x) * bf_lo(uv.x);
    acc = fmaf(bf_hi(wv.x), bf_hi(uv.x), acc);
    acc = fmaf(bf_lo(wv.y), bf_lo(uv.y), acc);
    acc = fmaf(bf_hi(wv.y), bf_hi(uv.y), acc);
    acc = fmaf(bf_lo(wv.z), bf_lo(uv.z), acc);
    acc = fmaf(bf_hi(wv.z), bf_hi(uv.z), acc);
    acc = fmaf(bf_lo(wv.w), bf_lo(uv.w), acc);
    acc = fmaf(bf_hi(wv.w), bf_hi(uv.w), acc);
    return acc;
}

__device__ __forceinline__ vuint4 pack8bf(const float acc[8]) {
    vuint4 p;
    p.x = (unsigned)f2bf(acc[0]) | ((unsigned)f2bf(acc[1]) << 16);
    p.y = (unsigned)f2bf(acc[2]) | ((unsigned)f2bf(acc[3]) << 16);
    p.z = (unsigned)f2bf(acc[4]) | ((unsigned)f2bf(acc[5]) << 16);
    p.w = (unsigned)f2bf(acc[6]) | ((unsigned)f2bf(acc[7]) << 16);
    return p;
}

__device__ __forceinline__ void build_w_row(
    const float* __restrict__ core0, const float* __restrict__ core1,
    int s0, int s1, vuint4* __restrict__ wbf)
{
    float acc[8] = {0.f, 0.f, 0.f, 0.f, 0.f, 0.f, 0.f, 0.f};
#pragma unroll
    for (int r = 0; r < 8; ++r) {
        const float c = core0[s0 * 8 + r];
        const float* row = core1 + (r * (NS * 8) + s1 * 8);
        const float4 lo = *(const float4*)row;
        const float4 hi = *(const float4*)(row + 4);
        acc[0] = fmaf(c, lo.x, acc[0]);
        acc[1] = fmaf(c, lo.y, acc[1]);
        acc[2] = fmaf(c, lo.z, acc[2]);
        acc[3] = fmaf(c, lo.w, acc[3]);
        acc[4] = fmaf(c, hi.x, acc[4]);
        acc[5] = fmaf(c, hi.y, acc[5]);
        acc[6] = fmaf(c, hi.z, acc[6]);
        acc[7] = fmaf(c, hi.w, acc[7]);
    }
    wbf[s0 * NS + s1] = pack8bf(acc);
}

__device__ __forceinline__ void build_u_row(
    const float* __restrict__ core2, const float* __restrict__ core3,
    int q, vuint4* __restrict__ ubf)
{
    const int s2 = q >> 6;
    const int a  = q & (NA - 1);
    float c3[8];
#pragma unroll
    for (int s = 0; s < 8; ++s) c3[s] = core3[s * NA + a];
    float acc[8];
#pragma unroll
    for (int r = 0; r < 8; ++r) {
        const float* row = core2 + (r * (NS * 8) + s2 * 8);
        const float4 lo = *(const float4*)row;
        const float4 hi = *(const float4*)(row + 4);
        acc[r] = lo.x * c3[0] + lo.y * c3[1] + lo.z * c3[2] + lo.w * c3[3] +
                 hi.x * c3[4] + hi.y * c3[5] + hi.z * c3[6] + hi.w * c3[7];
    }
    ubf[q] = pack8bf(acc);
}

// ---------- precompute: blocks [0,256) build w, [256,320) build u
__global__ __launch_bounds__(256) void qt_make_tables(
    const float* __restrict__ core0,
    const float* __restrict__ core1,
    const float* __restrict__ core2,
    const float* __restrict__ core3,
    vuint4* __restrict__ wbf,
    vuint4* __restrict__ ubf)
{
    const int blk = blockIdx.x;
    if (blk < NS) {
        build_w_row(core0, core1, blk, threadIdx.x, wbf);
    } else {
        build_u_row(core2, core3, (blk - NS) * 256 + threadIdx.x, ubf);
    }
}

// ---------- main: 4 samples/thread, nt gathers (L1-bypass)
__global__ __launch_bounds__(256) void qt_main4(
    const vint4* __restrict__ states4,
    const vint4* __restrict__ actions4,
    const vuint4* __restrict__ wbf,
    const vuint4* __restrict__ ubf,
    vfloat4* __restrict__ out4)
{
    const int t = blockIdx.x * blockDim.x + threadIdx.x;  // t < B/4

    const vint4 sa = __builtin_nontemporal_load(&states4[3 * t + 0]);
    const vint4 sb = __builtin_nontemporal_load(&states4[3 * t + 1]);
    const vint4 sc = __builtin_nontemporal_load(&states4[3 * t + 2]);
    const vint4 ac = __builtin_nontemporal_load(&actions4[t]);

    // sample 0: (sa.x, sa.y, sa.z, ac.x)
    // sample 1: (sa.w, sb.x, sb.y, ac.y)
    // sample 2: (sb.z, sb.w, sc.x, ac.z)
    // sample 3: (sc.y, sc.z, sc.w, ac.w)
    const vuint4 w0 = __builtin_nontemporal_load(&wbf[sa.x * NS + sa.y]);
    const vuint4 u0 = __builtin_nontemporal_load(&ubf[sa.z * NA + ac.x]);
    const vuint4 w1 = __builtin_nontemporal_load(&wbf[sa.w * NS + sb.x]);
    const vuint4 u1 = __builtin_nontemporal_load(&ubf[sb.y * NA + ac.y]);
    const vuint4 w2 = __builtin_nontemporal_load(&wbf[sb.z * NS + sb.w]);
    const vuint4 u2 = __builtin_nontemporal_load(&ubf[sc.x * NA + ac.z]);
    const vuint4 w3 = __builtin_nontemporal_load(&wbf[sc.y * NS + sc.z]);
    const vuint4 u3 = __builtin_nontemporal_load(&ubf[sc.w * NA + ac.w]);

    vfloat4 o;
    o.x = dot8bf(w0, u0);
    o.y = dot8bf(w1, u1);
    o.z = dot8bf(w2, u2);
    o.w = dot8bf(w3, u3);

    __builtin_nontemporal_store(o, &out4[t]);
}

// ---------- fallback (round-1 kernel) if ws is too small
__global__ __launch_bounds__(256) void qt_direct(
    const int* __restrict__ states,
    const int* __restrict__ actions,
    const float* __restrict__ core0,
    const float* __restrict__ core1,
    const float* __restrict__ core2,
    const float* __restrict__ core3,
    float* __restrict__ out)
{
    const int b = blockIdx.x * blockDim.x + threadIdx.x;
    if (b >= QT_B) return;

    const int s0 = states[3 * b + 0];
    const int s1 = states[3 * b + 1];
    const int s2 = states[3 * b + 2];
    const int a  = actions[b];

    const float4 v0lo = *(const float4*)(core0 + s0 * 8);
    const float4 v0hi = *(const float4*)(core0 + s0 * 8 + 4);
    float v0[8] = {v0lo.x, v0lo.y, v0lo.z, v0lo.w,
                   v0hi.x, v0hi.y, v0hi.z, v0hi.w};

    float v1[8] = {0.f};
#pragma unroll
    for (int r = 0; r < 8; ++r) {
        const float* row = core1 + (r * (NS * 8) + s1 * 8);
        const float4 lo = *(const float4*)row;
        const float4 hi = *(const float4*)(row + 4);
        const float c = v0[r];
        v1[0] = fmaf(c, lo.x, v1[0]); v1[1] = fmaf(c, lo.y, v1[1]);
        v1[2] = fmaf(c, lo.z, v1[2]); v1[3] = fmaf(c, lo.w, v1[3]);
        v1[4] = fmaf(c, hi.x, v1[4]); v1[5] = fmaf(c, hi.y, v1[5]);
        v1[6] = fmaf(c, hi.z, v1[6]); v1[7] = fmaf(c, hi.w, v1[7]);
    }

    float v2[8] = {0.f};
#pragma unroll
    for (int r = 0; r < 8; ++r) {
        const float* row = core2 + (r * (NS * 8) + s2 * 8);
        const float4 lo = *(const float4*)row;
        const float4 hi = *(const float4*)(row + 4);
        const float c = v1[r];
        v2[0] = fmaf(c, lo.x, v2[0]); v2[1] = fmaf(c, lo.y, v2[1]);
        v2[2] = fmaf(c, lo.z, v2[2]); v2[3] = fmaf(c, lo.w, v2[3]);
        v2[4] = fmaf(c, hi.x, v2[4]); v2[5] = fmaf(c, hi.y, v2[5]);
        v2[6] = fmaf(c, hi.z, v2[6]); v2[7] = fmaf(c, hi.w, v2[7]);
    }

    float acc = 0.f;
#pragma unroll
    for (int r = 0; r < 8; ++r) acc = fmaf(v2[r], core3[r * NA + a], acc);
    out[b] = acc;
}

extern "C" void kernel_launch(void* const* d_in, const int* in_sizes, int n_in,
                              void* d_out, int out_size, void* d_ws, size_t ws_size,
                              hipStream_t stream) {
    const int*   states  = (const int*)d_in[0];
    const int*   actions = (const int*)d_in[1];
    const float* core0   = (const float*)d_in[2];
    const float* core1   = (const float*)d_in[3];
    const float* core2   = (const float*)d_in[4];
    const float* core3   = (const float*)d_in[5];
    float* out = (float*)d_out;

    const size_t need = (size_t)(W_ROWS + U_ROWS) * 16;  // 1.25 MB
    if (ws_size >= need) {
        vuint4* wbf = (vuint4*)d_ws;
        vuint4* ubf = wbf + W_ROWS;

        qt_make_tables<<<NS + U_ROWS / 256, 256, 0, stream>>>(
            core0, core1, core2, core3, wbf, ubf);

        qt_main4<<<MAIN_BLOCKS, 256, 0, stream>>>(
            (const vint4*)states, (const vint4*)actions, wbf, ubf,
            (vfloat4*)out);
    } else {
        qt_direct<<<QT_B / 256, 256, 0, stream>>>(states, actions, core0, core1,
                                                  core2, core3, out);
    }
}

// Round 9
// 21.323 us; speedup vs baseline: 7.4906x; 1.2242x over previous
//
#include <hip/hip_runtime.h>

// QTLayer via tensor-train composition, bf16 tables, 4 samples/thread:
//   out[b] = core0[s0]·M1(s1)·M2(s2)·c3(a) = w[s0*256+s1] · u[s2*64+a]
// w = core0·core1 (64K rows), u = core2·core3 (16K rows), bf16x8 rows (16 B).
// Two-kernel split (fusion refuted twice: R6 token-spin, R7 grid.sync ~120us).
// R9 experiment: table gathers via inline-asm global_load_dwordx4 with sc0
// (bypass L1, stay L2-temporal) — discriminates L1-line-fill-BW (T1) from
// L2-request-rate (T3) as the gather-phase bound. R8's `nt` was the wrong
// flag (evict-first in L2 too -> streams evicted the tables, +4.8us).
// Streams (indices in, out) keep nontemporal; tables stay plain elsewhere.

#define QT_B (1 << 20)
#define NS 256
#define NA 64

#define W_ROWS (NS * NS)   // 65536
#define U_ROWS (NS * NA)   // 16384
#define MAIN_BLOCKS (QT_B / 4 / 256)   // 1024

typedef int          vint4   __attribute__((ext_vector_type(4)));
typedef unsigned int vuint4  __attribute__((ext_vector_type(4)));
typedef float        vfloat4 __attribute__((ext_vector_type(4)));

__device__ __forceinline__ unsigned short f2bf(float x) {
    unsigned int u = __float_as_uint(x);
    unsigned int r = (u + 0x7fffu + ((u >> 16) & 1u)) >> 16;  // RNE
    return (unsigned short)r;
}

__device__ __forceinline__ float bf_lo(unsigned int u) {
    return __uint_as_float(u << 16);
}
__device__ __forceinline__ float bf_hi(unsigned int u) {
    return __uint_as_float(u & 0xffff0000u);
}

__device__ __forceinline__ float dot8bf(vuint4 wv, vuint4 uv) {
    float acc;
    acc = bf_lo(wv.x) * bf_lo(uv.x);
    acc = fmaf(bf_hi(wv.x), bf_hi(uv.x), acc);
    acc = fmaf(bf_lo(wv.y), bf_lo(uv.y), acc);
    acc = fmaf(bf_hi(wv.y), bf_hi(uv.y), acc);
    acc = fmaf(bf_lo(wv.z), bf_lo(uv.z), acc);
    acc = fmaf(bf_hi(wv.z), bf_hi(uv.z), acc);
    acc = fmaf(bf_lo(wv.w), bf_lo(uv.w), acc);
    acc = fmaf(bf_hi(wv.w), bf_hi(uv.w), acc);
    return acc;
}

__device__ __forceinline__ vuint4 pack8bf(const float acc[8]) {
    vuint4 p;
    p.x = (unsigned)f2bf(acc[0]) | ((unsigned)f2bf(acc[1]) << 16);
    p.y = (unsigned)f2bf(acc[2]) | ((unsigned)f2bf(acc[3]) << 16);
    p.z = (unsigned)f2bf(acc[4]) | ((unsigned)f2bf(acc[5]) << 16);
    p.w = (unsigned)f2bf(acc[6]) | ((unsigned)f2bf(acc[7]) << 16);
    return p;
}

__device__ __forceinline__ void build_w_row(
    const float* __restrict__ core0, const float* __restrict__ core1,
    int s0, int s1, vuint4* __restrict__ wbf)
{
    float acc[8] = {0.f, 0.f, 0.f, 0.f, 0.f, 0.f, 0.f, 0.f};
#pragma unroll
    for (int r = 0; r < 8; ++r) {
        const float c = core0[s0 * 8 + r];
        const float* row = core1 + (r * (NS * 8) + s1 * 8);
        const float4 lo = *(const float4*)row;
        const float4 hi = *(const float4*)(row + 4);
        acc[0] = fmaf(c, lo.x, acc[0]);
        acc[1] = fmaf(c, lo.y, acc[1]);
        acc[2] = fmaf(c, lo.z, acc[2]);
        acc[3] = fmaf(c, lo.w, acc[3]);
        acc[4] = fmaf(c, hi.x, acc[4]);
        acc[5] = fmaf(c, hi.y, acc[5]);
        acc[6] = fmaf(c, hi.z, acc[6]);
        acc[7] = fmaf(c, hi.w, acc[7]);
    }
    wbf[s0 * NS + s1] = pack8bf(acc);
}

__device__ __forceinline__ void build_u_row(
    const float* __restrict__ core2, const float* __restrict__ core3,
    int q, vuint4* __restrict__ ubf)
{
    const int s2 = q >> 6;
    const int a  = q & (NA - 1);
    float c3[8];
#pragma unroll
    for (int s = 0; s < 8; ++s) c3[s] = core3[s * NA + a];
    float acc[8];
#pragma unroll
    for (int r = 0; r < 8; ++r) {
        const float* row = core2 + (r * (NS * 8) + s2 * 8);
        const float4 lo = *(const float4*)row;
        const float4 hi = *(const float4*)(row + 4);
        acc[r] = lo.x * c3[0] + lo.y * c3[1] + lo.z * c3[2] + lo.w * c3[3] +
                 hi.x * c3[4] + hi.y * c3[5] + hi.z * c3[6] + hi.w * c3[7];
    }
    ubf[q] = pack8bf(acc);
}

// ---------- precompute: blocks [0,256) build w, [256,320) build u
__global__ __launch_bounds__(256) void qt_make_tables(
    const float* __restrict__ core0,
    const float* __restrict__ core1,
    const float* __restrict__ core2,
    const float* __restrict__ core3,
    vuint4* __restrict__ wbf,
    vuint4* __restrict__ ubf)
{
    const int blk = blockIdx.x;
    if (blk < NS) {
        build_w_row(core0, core1, blk, threadIdx.x, wbf);
    } else {
        build_u_row(core2, core3, (blk - NS) * 256 + threadIdx.x, ubf);
    }
}

// ---------- main: 4 samples/thread, sc0 gathers (L1-bypass, L2-temporal)
__global__ __launch_bounds__(256) void qt_main4(
    const vint4* __restrict__ states4,
    const vint4* __restrict__ actions4,
    const vuint4* __restrict__ wbf,
    const vuint4* __restrict__ ubf,
    vfloat4* __restrict__ out4)
{
    const int t = blockIdx.x * blockDim.x + threadIdx.x;  // t < B/4

    const vint4 sa = __builtin_nontemporal_load(&states4[3 * t + 0]);
    const vint4 sb = __builtin_nontemporal_load(&states4[3 * t + 1]);
    const vint4 sc = __builtin_nontemporal_load(&states4[3 * t + 2]);
    const vint4 ac = __builtin_nontemporal_load(&actions4[t]);

    // sample 0: (sa.x, sa.y, sa.z, ac.x)
    // sample 1: (sa.w, sb.x, sb.y, ac.y)
    // sample 2: (sb.z, sb.w, sc.x, ac.z)
    // sample 3: (sc.y, sc.z, sc.w, ac.w)
    const vuint4* aw0 = &wbf[sa.x * NS + sa.y];
    const vuint4* au0 = &ubf[sa.z * NA + ac.x];
    const vuint4* aw1 = &wbf[sa.w * NS + sb.x];
    const vuint4* au1 = &ubf[sb.y * NA + ac.y];
    const vuint4* aw2 = &wbf[sb.z * NS + sb.w];
    const vuint4* au2 = &ubf[sc.x * NA + ac.z];
    const vuint4* aw3 = &wbf[sc.y * NS + sc.z];
    const vuint4* au3 = &ubf[sc.w * NA + ac.w];

    vuint4 w0, u0, w1, u1, w2, u2, w3, u3;
    // All 8 gathers issued back-to-back (full MLP), one waitcnt. sc0 =
    // bypass L1 (no 64B line fill), service from L2, normal L2 retention.
    asm volatile(
        "global_load_dwordx4 %0, %8, off sc0\n\t"
        "global_load_dwordx4 %1, %9, off sc0\n\t"
        "global_load_dwordx4 %2, %10, off sc0\n\t"
        "global_load_dwordx4 %3, %11, off sc0\n\t"
        "global_load_dwordx4 %4, %12, off sc0\n\t"
        "global_load_dwordx4 %5, %13, off sc0\n\t"
        "global_load_dwordx4 %6, %14, off sc0\n\t"
        "global_load_dwordx4 %7, %15, off sc0\n\t"
        "s_waitcnt vmcnt(0)"
        : "=&v"(w0), "=&v"(u0), "=&v"(w1), "=&v"(u1),
          "=&v"(w2), "=&v"(u2), "=&v"(w3), "=&v"(u3)
        : "v"(aw0), "v"(au0), "v"(aw1), "v"(au1),
          "v"(aw2), "v"(au2), "v"(aw3), "v"(au3)
        : "memory");

    vfloat4 o;
    o.x = dot8bf(w0, u0);
    o.y = dot8bf(w1, u1);
    o.z = dot8bf(w2, u2);
    o.w = dot8bf(w3, u3);

    __builtin_nontemporal_store(o, &out4[t]);
}

// ---------- fallback (round-1 kernel) if ws is too small
__global__ __launch_bounds__(256) void qt_direct(
    const int* __restrict__ states,
    const int* __restrict__ actions,
    const float* __restrict__ core0,
    const float* __restrict__ core1,
    const float* __restrict__ core2,
    const float* __restrict__ core3,
    float* __restrict__ out)
{
    const int b = blockIdx.x * blockDim.x + threadIdx.x;
    if (b >= QT_B) return;

    const int s0 = states[3 * b + 0];
    const int s1 = states[3 * b + 1];
    const int s2 = states[3 * b + 2];
    const int a  = actions[b];

    const float4 v0lo = *(const float4*)(core0 + s0 * 8);
    const float4 v0hi = *(const float4*)(core0 + s0 * 8 + 4);
    float v0[8] = {v0lo.x, v0lo.y, v0lo.z, v0lo.w,
                   v0hi.x, v0hi.y, v0hi.z, v0hi.w};

    float v1[8] = {0.f};
#pragma unroll
    for (int r = 0; r < 8; ++r) {
        const float* row = core1 + (r * (NS * 8) + s1 * 8);
        const float4 lo = *(const float4*)row;
        const float4 hi = *(const float4*)(row + 4);
        const float c = v0[r];
        v1[0] = fmaf(c, lo.x, v1[0]); v1[1] = fmaf(c, lo.y, v1[1]);
        v1[2] = fmaf(c, lo.z, v1[2]); v1[3] = fmaf(c, lo.w, v1[3]);
        v1[4] = fmaf(c, hi.x, v1[4]); v1[5] = fmaf(c, hi.y, v1[5]);
        v1[6] = fmaf(c, hi.z, v1[6]); v1[7] = fmaf(c, hi.w, v1[7]);
    }

    float v2[8] = {0.f};
#pragma unroll
    for (int r = 0; r < 8; ++r) {
        const float* row = core2 + (r * (NS * 8) + s2 * 8);
        const float4 lo = *(const float4*)row;
        const float4 hi = *(const float4*)(row + 4);
        const float c = v1[r];
        v2[0] = fmaf(c, lo.x, v2[0]); v2[1] = fmaf(c, lo.y, v2[1]);
        v2[2] = fmaf(c, lo.z, v2[2]); v2[3] = fmaf(c, lo.w, v2[3]);
        v2[4] = fmaf(c, hi.x, v2[4]); v2[5] = fmaf(c, hi.y, v2[5]);
        v2[6] = fmaf(c, hi.z, v2[6]); v2[7] = fmaf(c, hi.w, v2[7]);
    }

    float acc = 0.f;
#pragma unroll
    for (int r = 0; r < 8; ++r) acc = fmaf(v2[r], core3[r * NA + a], acc);
    out[b] = acc;
}

extern "C" void kernel_launch(void* const* d_in, const int* in_sizes, int n_in,
                              void* d_out, int out_size, void* d_ws, size_t ws_size,
                              hipStream_t stream) {
    const int*   states  = (const int*)d_in[0];
    const int*   actions = (const int*)d_in[1];
    const float* core0   = (const float*)d_in[2];
    const float* core1   = (const float*)d_in[3];
    const float* core2   = (const float*)d_in[4];
    const float* core3   = (const float*)d_in[5];
    float* out = (float*)d_out;

    const size_t need = (size_t)(W_ROWS + U_ROWS) * 16;  // 1.25 MB
    if (ws_size >= need) {
        vuint4* wbf = (vuint4*)d_ws;
        vuint4* ubf = wbf + W_ROWS;

        qt_make_tables<<<NS + U_ROWS / 256, 256, 0, stream>>>(
            core0, core1, core2, core3, wbf, ubf);

        qt_main4<<<MAIN_BLOCKS, 256, 0, stream>>>(
            (const vint4*)states, (const vint4*)actions, wbf, ubf,
            (vfloat4*)out);
    } else {
        qt_direct<<<QT_B / 256, 256, 0, stream>>>(states, actions, core0, core1,
                                                  core2, core3, out);
    }
}